// Round 10
// baseline (3287.077 us; speedup 1.0000x reference)
//
#include <hip/hip_runtime.h>
#include <hip/hip_bf16.h>

// ---------------------------------------------------------------------------
// MatchingNetwork forward, f32. Fused conv+stats+maxpool trunk; BN+ReLU of
// layer i applied inline while staging layer i+1's inputs (bit-identical to
// a separate bnapply pass; OOB taps stage exact 0 = post-BN zero padding).
// Activations: [g_local*32+i][h][w][c], c=64 contiguous.
// ---------------------------------------------------------------------------

#define NG 25
#define NI 32

__device__ __forceinline__ float sigm(float x) { return 1.f / (1.f + expf(-x)); }

// ---------------- Layer 1: conv(CIN=3) + stats + 2x2 pool -------------------
__device__ __forceinline__ void loadcol3(float* dst, const float (*sIn)[256],
                                         int ry, int wcol) {
    if ((unsigned)wcol < 84u) {
        #pragma unroll
        for (int kh = 0; kh < 3; ++kh)
            #pragma unroll
            for (int ci = 0; ci < 3; ++ci)
                dst[kh * 3 + ci] = sIn[ry + kh][wcol * 3 + ci];
    } else {
        #pragma unroll
        for (int t = 0; t < 9; ++t) dst[t] = 0.f;
    }
}

__device__ __forceinline__ float emit3(const float* L, const float* M,
                                       const float* R, const float* wreg) {
    float o = 0.f;
    #pragma unroll
    for (int t = 0; t < 9; ++t) {
        o = fmaf(L[t], wreg[t], o);
        o = fmaf(M[t], wreg[9 + t], o);
        o = fmaf(R[t], wreg[18 + t], o);
    }
    return o;
}

// grid (gx, 21), block 256 = 4 conv rows x 64 co. Writes pooled PRE-BN.
__global__ __launch_bounds__(256)
void conv3pool_kernel(const float* __restrict__ xs, const float* __restrict__ xq,
                      const float* __restrict__ wk, float* __restrict__ pool1,
                      float* __restrict__ part, int g0) {
    int gi = blockIdx.x;
    int gl = gi >> 5, i = gi & 31;
    int g = g0 + gl;
    int band = blockIdx.y;
    int co = threadIdx.x & 63;
    int ry = threadIdx.x >> 6;
    const float* base = (g < 20) ? xs + (size_t)(i * 20 + g) * (84 * 84 * 3)
                                 : xq + (size_t)(i * 5 + (g - 20)) * (84 * 84 * 3);
    __shared__ float sIn[6][256];
    __shared__ float red[2][4][64];
    __shared__ float plds[4][6][64];
    int r0 = band * 4 - 1;
    for (int t = 0; t < 6; ++t) {
        int idx = t * 256 + threadIdx.x;
        if (idx < 6 * 252) {
            int rr = idx / 252, cc = idx - rr * 252;
            int sr = r0 + rr;
            sIn[rr][cc] = ((unsigned)sr < 84u) ? base[(size_t)sr * 252 + cc] : 0.f;
        }
    }
    float wreg[27];
    #pragma unroll
    for (int kh = 0; kh < 3; ++kh)
        #pragma unroll
        for (int kw = 0; kw < 3; ++kw)
            #pragma unroll
            for (int ci = 0; ci < 3; ++ci)
                wreg[kw * 9 + kh * 3 + ci] = wk[(size_t)((kh * 3 + kw) * 3 + ci) * 64 + co];
    __syncthreads();

    float s = 0.f, s2 = 0.f;
    float A[9], B[9], Cc[9];
    int prow42 = band * 2 + (ry >> 1);

    #pragma unroll 1
    for (int grp = 0; grp < 7; ++grp) {
        int cb = grp * 12;
        float m6[6];
        float pend = 0.f;
        loadcol3(A, sIn, ry, cb - 1);
        loadcol3(B, sIn, ry, cb);
        #pragma unroll
        for (int rpt = 0; rpt < 4; ++rpt) {
            int c = cb + rpt * 3;
            loadcol3(Cc, sIn, ry, c + 1);
            float o0 = emit3(A, B, Cc, wreg);
            loadcol3(A, sIn, ry, c + 2);
            float o1 = emit3(B, Cc, A, wreg);
            loadcol3(B, sIn, ry, c + 3);
            float o2 = emit3(Cc, A, B, wreg);
            s += o0; s2 = fmaf(o0, o0, s2);
            s += o1; s2 = fmaf(o1, o1, s2);
            s += o2; s2 = fmaf(o2, o2, s2);
            if (rpt == 0)      { m6[0] = fmaxf(o0, o1); pend = o2; }
            else if (rpt == 1) { m6[1] = fmaxf(pend, o0); m6[2] = fmaxf(o1, o2); }
            else if (rpt == 2) { m6[3] = fmaxf(o0, o1); pend = o2; }
            else               { m6[4] = fmaxf(pend, o0); m6[5] = fmaxf(o1, o2); }
        }
        __syncthreads();
        #pragma unroll
        for (int t = 0; t < 6; ++t) plds[ry][t][co] = m6[t];
        __syncthreads();
        if ((ry & 1) == 0) {
            #pragma unroll
            for (int t = 0; t < 6; ++t) {
                float pm = fmaxf(plds[ry][t][co], plds[ry + 1][t][co]);
                pool1[(((size_t)gi * 42 + prow42) * 42 + grp * 6 + t) * 64 + co] = pm;
            }
        }
    }

    red[0][ry][co] = s; red[1][ry][co] = s2;
    __syncthreads();
    if (ry == 0) {
        float ts  = red[0][0][co] + red[0][1][co] + red[0][2][co] + red[0][3][co];
        float ts2 = red[1][0][co] + red[1][1][co] + red[1][2][co] + red[1][3][co];
        size_t prow = (size_t)blockIdx.y * gridDim.x + blockIdx.x;
        part[prow * 128 + co] = ts;
        part[prow * 128 + 64 + co] = ts2;
    }
}

// ---------------- Layers 2-3: conv(CIN=64) + inline-BN-in + stats + pool ----
// Reads PRE-BN pooled input, applies relu(fma(sc,x,sh)) while staging.
template<int D, int TR, int TC>
__global__ __launch_bounds__(256)
void conv64p_kernel(const float* __restrict__ act, const float* __restrict__ wk,
                    const float* __restrict__ bnprev,
                    float* __restrict__ poolout, float* __restrict__ part) {
    constexpr int POS = TR * TC;
    constexpr int APT = POS / 16;        // acc rows per thread
    constexpr int SPL = 256 / POS;       // staging threads per position
    constexpr int CIW = 64 / SPL;        // ci span per staging thread (=4*APT)
    constexpr int nCT = (D + TC - 1) / TC;
    constexpr int PD = D / 2;
    int gi = blockIdx.x;
    int gl = gi >> 5;
    int rt = blockIdx.y / nCT, ct = blockIdx.y % nCT;
    int r0 = rt * TR, c0 = ct * TC;
    int tx = threadIdx.x & 15;
    int ty = threadIdx.x >> 4;
    int sr = threadIdx.x / SPL;          // staged position p'
    int sq = threadIdx.x % SPL;          // ci chunk
    const float* in = act + (size_t)gi * D * D * 64;
    __shared__ __align__(16) float As[64][POS + 8];
    __shared__ __align__(16) float Bs[64][68];
    __shared__ float bnl[128];
    if (threadIdx.x < 128) bnl[threadIdx.x] = bnprev[gl * 128 + threadIdx.x];
    float acc[APT][4];
    #pragma unroll
    for (int a = 0; a < APT; ++a)
        #pragma unroll
        for (int b = 0; b < 4; ++b) acc[a][b] = 0.f;

    int tr = sr / TC, tc = sr % TC;
    int h = r0 + tr, w = c0 + tc;
    bool pval = (h < D) && (w < D);
    __syncthreads();   // bnl visible

    #pragma unroll 1
    for (int tap = 0; tap < 9; ++tap) {
        int kh = tap / 3, kw = tap - kh * 3;
        int hi = h + kh - 1, wi = w + kw - 1;
        float4 vt[APT];
        #pragma unroll
        for (int t = 0; t < APT; ++t) vt[t] = make_float4(0.f, 0.f, 0.f, 0.f);
        if (pval && (unsigned)hi < (unsigned)D && (unsigned)wi < (unsigned)D) {
            const float4* src = (const float4*)(in + ((size_t)hi * D + wi) * 64 + sq * CIW);
            #pragma unroll
            for (int t = 0; t < APT; ++t) {
                float4 x = src[t];
                int cb = sq * CIW + t * 4;
                x.x = fmaxf(0.f, fmaf(bnl[cb + 0], x.x, bnl[64 + cb + 0]));
                x.y = fmaxf(0.f, fmaf(bnl[cb + 1], x.y, bnl[64 + cb + 1]));
                x.z = fmaxf(0.f, fmaf(bnl[cb + 2], x.z, bnl[64 + cb + 2]));
                x.w = fmaxf(0.f, fmaf(bnl[cb + 3], x.w, bnl[64 + cb + 3]));
                vt[t] = x;
            }
        }
        int rB = threadIdx.x >> 2, qB = threadIdx.x & 3;
        const float4* wsrc = (const float4*)(wk + (size_t)(tap * 64 + rB) * 64 + qB * 16);
        float4 b0 = wsrc[0], b1 = wsrc[1], b2 = wsrc[2], b3 = wsrc[3];
        __syncthreads();   // previous GEMM done before overwriting LDS
        #pragma unroll
        for (int t = 0; t < APT; ++t) {
            const float* ev = (const float*)&vt[t];
            As[sq * CIW + t * 4 + 0][sr] = ev[0];
            As[sq * CIW + t * 4 + 1][sr] = ev[1];
            As[sq * CIW + t * 4 + 2][sr] = ev[2];
            As[sq * CIW + t * 4 + 3][sr] = ev[3];
        }
        {
            float4* bd = (float4*)&Bs[rB][qB * 16];
            bd[0] = b0; bd[1] = b1; bd[2] = b2; bd[3] = b3;
        }
        __syncthreads();
        #pragma unroll 16
        for (int k = 0; k < 64; ++k) {
            float4 b4 = *(const float4*)&Bs[k][tx * 4];
            const float* bp = (const float*)&b4;
            #pragma unroll
            for (int u = 0; u < APT / 4; ++u) {
                float4 a4 = *(const float4*)&As[k][ty * APT + u * 4];
                const float* ap = (const float*)&a4;
                #pragma unroll
                for (int ii = 0; ii < 4; ++ii)
                    #pragma unroll
                    for (int jj = 0; jj < 4; ++jj)
                        acc[u * 4 + ii][jj] = fmaf(ap[ii], bp[jj], acc[u * 4 + ii][jj]);
            }
        }
    }

    // stats partials (invalid positions contribute exact zeros)
    float s[4], s2[4];
    #pragma unroll
    for (int j = 0; j < 4; ++j) {
        s[j] = 0.f; s2[j] = 0.f;
        #pragma unroll
        for (int ii = 0; ii < APT; ++ii) {
            float a = acc[ii][j];
            s[j] += a; s2[j] = fmaf(a, a, s2[j]);
        }
    }
    __syncthreads();   // GEMM done; reuse As (conv values) and Bs (stats red)
    float* red = &Bs[0][0];
    #pragma unroll
    for (int j = 0; j < 4; ++j) {
        red[(size_t)threadIdx.x * 8 + j] = s[j];
        red[(size_t)threadIdx.x * 8 + 4 + j] = s2[j];
    }
    float* lds2 = &As[0][0];   // [POS][64]
    #pragma unroll
    for (int ii = 0; ii < APT; ++ii)
        #pragma unroll
        for (int jj = 0; jj < 4; ++jj)
            lds2[(size_t)(ty * APT + ii) * 64 + tx * 4 + jj] = acc[ii][jj];
    __syncthreads();
    if (ty == 0) {
        float ts[8] = {0,0,0,0,0,0,0,0};
        for (int t = 0; t < 16; ++t)
            #pragma unroll
            for (int u = 0; u < 8; ++u) ts[u] += red[(size_t)(t * 16 + tx) * 8 + u];
        size_t prow = (size_t)blockIdx.y * gridDim.x + blockIdx.x;
        #pragma unroll
        for (int j = 0; j < 4; ++j) {
            part[prow * 128 + tx * 4 + j] = ts[j];
            part[prow * 128 + 64 + tx * 4 + j] = ts[4 + j];
        }
    }
    // 2x2 max pool from lds2 -> pooled PRE-BN store
    constexpr int NP = (TR / 2) * (TC / 2) * 64;
    for (int o = threadIdx.x; o < NP; o += 256) {
        int cell = o >> 6, ch = o & 63;
        int pr = cell / (TC / 2), pc = cell % (TC / 2);
        int p00 = (2 * pr) * TC + 2 * pc;
        float m = fmaxf(fmaxf(lds2[(size_t)p00 * 64 + ch], lds2[(size_t)(p00 + 1) * 64 + ch]),
                        fmaxf(lds2[(size_t)(p00 + TC) * 64 + ch], lds2[(size_t)(p00 + TC + 1) * 64 + ch]));
        int gpr = rt * (TR / 2) + pr, gpc = ct * (TC / 2) + pc;
        if (gpr < PD && gpc < PD)
            poolout[(((size_t)gi * PD + gpr) * PD + gpc) * 64 + ch] = m;
    }
}

// ---------------- Layer 4 conv (CIN=64) + inline-BN-in, 64x64 tile ----------
__global__ __launch_bounds__(256)
void conv64_kernel(const float* __restrict__ act, const float* __restrict__ wk,
                   const float* __restrict__ bnprev,
                   float* __restrict__ raw, float* __restrict__ part,
                   int H, int W) {
    int gi = blockIdx.x;
    int gl = gi >> 5;
    int HW = H * W;
    int p0 = blockIdx.y * 64;
    int tx = threadIdx.x & 15;
    int ty = threadIdx.x >> 4;
    int r  = threadIdx.x >> 2;
    int q  = threadIdx.x & 3;
    const float* in = act + (size_t)gi * HW * 64;
    __shared__ float As[64][68];
    __shared__ float Bs[64][68];
    __shared__ float bnl[128];
    if (threadIdx.x < 128) bnl[threadIdx.x] = bnprev[gl * 128 + threadIdx.x];
    float acc[4][4];
    #pragma unroll
    for (int a = 0; a < 4; ++a)
        #pragma unroll
        for (int b = 0; b < 4; ++b) acc[a][b] = 0.f;

    int p = p0 + r;
    bool pv = p < HW;
    int h = 0, w = 0;
    if (pv) { h = p / W; w = p - h * W; }
    __syncthreads();

    #pragma unroll 1
    for (int tap = 0; tap < 9; ++tap) {
        int kh = tap / 3, kw = tap - kh * 3;
        float4 v0 = {0,0,0,0}, v1 = v0, v2 = v0, v3 = v0;
        int hi = h + kh - 1, wi = w + kw - 1;
        if (pv && (unsigned)hi < (unsigned)H && (unsigned)wi < (unsigned)W) {
            const float4* src = (const float4*)(in + ((size_t)hi * W + wi) * 64 + q * 16);
            v0 = src[0]; v1 = src[1]; v2 = src[2]; v3 = src[3];
            int cb = q * 16;
            float4* vv[4] = { &v0, &v1, &v2, &v3 };
            #pragma unroll
            for (int t = 0; t < 4; ++t) {
                float4& x = *vv[t];
                int cc = cb + t * 4;
                x.x = fmaxf(0.f, fmaf(bnl[cc + 0], x.x, bnl[64 + cc + 0]));
                x.y = fmaxf(0.f, fmaf(bnl[cc + 1], x.y, bnl[64 + cc + 1]));
                x.z = fmaxf(0.f, fmaf(bnl[cc + 2], x.z, bnl[64 + cc + 2]));
                x.w = fmaxf(0.f, fmaf(bnl[cc + 3], x.w, bnl[64 + cc + 3]));
            }
        }
        const float4* wsrc = (const float4*)(wk + (size_t)((tap * 64 + r)) * 64 + q * 16);
        float4 b0 = wsrc[0], b1 = wsrc[1], b2 = wsrc[2], b3 = wsrc[3];
        __syncthreads();
        {
            const float* e;
            e = (const float*)&v0;
            #pragma unroll
            for (int t = 0; t < 4; ++t) As[q * 16 + 0 + t][r] = e[t];
            e = (const float*)&v1;
            #pragma unroll
            for (int t = 0; t < 4; ++t) As[q * 16 + 4 + t][r] = e[t];
            e = (const float*)&v2;
            #pragma unroll
            for (int t = 0; t < 4; ++t) As[q * 16 + 8 + t][r] = e[t];
            e = (const float*)&v3;
            #pragma unroll
            for (int t = 0; t < 4; ++t) As[q * 16 + 12 + t][r] = e[t];
            float4* bd = (float4*)&Bs[r][q * 16];
            bd[0] = b0; bd[1] = b1; bd[2] = b2; bd[3] = b3;
        }
        __syncthreads();
        #pragma unroll
        for (int k = 0; k < 64; ++k) {
            float4 a4 = *(const float4*)&As[k][ty * 4];
            float4 b4 = *(const float4*)&Bs[k][tx * 4];
            const float* ap = (const float*)&a4;
            const float* bp = (const float*)&b4;
            #pragma unroll
            for (int ii = 0; ii < 4; ++ii)
                #pragma unroll
                for (int jj = 0; jj < 4; ++jj)
                    acc[ii][jj] = fmaf(ap[ii], bp[jj], acc[ii][jj]);
        }
    }

    #pragma unroll
    for (int ii = 0; ii < 4; ++ii) {
        int pp = p0 + ty * 4 + ii;
        if (pp < HW) {
            float4 o = { acc[ii][0], acc[ii][1], acc[ii][2], acc[ii][3] };
            *(float4*)(raw + ((size_t)gi * HW + pp) * 64 + tx * 4) = o;
        }
    }
    float s[4], s2[4];
    #pragma unroll
    for (int j = 0; j < 4; ++j) {
        s[j] = acc[0][j] + acc[1][j] + acc[2][j] + acc[3][j];
        s2[j] = acc[0][j]*acc[0][j] + acc[1][j]*acc[1][j] + acc[2][j]*acc[2][j] + acc[3][j]*acc[3][j];
    }
    __syncthreads();
    float* red = &As[0][0];
    #pragma unroll
    for (int j = 0; j < 4; ++j) {
        red[(ty * 16 + tx) * 8 + j] = s[j];
        red[(ty * 16 + tx) * 8 + 4 + j] = s2[j];
    }
    __syncthreads();
    if (ty == 0) {
        float ts[8] = {0,0,0,0,0,0,0,0};
        for (int t = 0; t < 16; ++t)
            #pragma unroll
            for (int u = 0; u < 8; ++u) ts[u] += red[(t * 16 + tx) * 8 + u];
        size_t prow = (size_t)blockIdx.y * gridDim.x + blockIdx.x;
        #pragma unroll
        for (int j = 0; j < 4; ++j) {
            part[prow * 128 + tx * 4 + j] = ts[j];
            part[prow * 128 + 64 + tx * 4 + j] = ts[4 + j];
        }
    }
}

// Deterministic reduce of partials -> (scale, shift). block 256 = 64c x 4-way.
__global__ __launch_bounds__(256)
void bn_finalize_kernel(const float* __restrict__ part,
                        const float* __restrict__ gamma,
                        const float* __restrict__ beta,
                        float* __restrict__ bnp, float invN, int nby, int gridx) {
    int g = blockIdx.x;
    int c = threadIdx.x & 63;
    int par = threadIdx.x >> 6;
    int nrows = nby * 32;
    float s = 0.f, s2 = 0.f;
    for (int rr = par; rr < nrows; rr += 4) {
        int by = rr >> 5, i = rr & 31;
        size_t row = (size_t)by * gridx + g * 32 + i;
        s  += part[row * 128 + c];
        s2 += part[row * 128 + 64 + c];
    }
    __shared__ float red[2][4][64];
    red[0][par][c] = s; red[1][par][c] = s2;
    __syncthreads();
    if (par == 0) {
        s  = red[0][0][c] + red[0][1][c] + red[0][2][c] + red[0][3][c];
        s2 = red[1][0][c] + red[1][1][c] + red[1][2][c] + red[1][3][c];
        float mean = s * invN;
        float var  = s2 * invN - mean * mean;
        float sc = gamma[c] * rsqrtf(var + 1e-3f);
        bnp[g * 128 + c] = sc;
        bnp[g * 128 + 64 + c] = beta[c] - sc * mean;
    }
}

// BN + ReLU + 2x2 maxpool (L4 raw -> emb slice).
__global__ __launch_bounds__(256)
void bnpool_kernel(const float* __restrict__ raw, const float* __restrict__ bnp,
                   float* __restrict__ outp, int H, int W, int PH, int PW,
                   int total) {
    int v = blockIdx.x * 256 + threadIdx.x;
    if (v >= total) return;
    int c4 = (v & 15) * 4;
    int pos = v >> 4;
    int PP = PH * PW;
    int gi = pos / PP;
    int pp = pos - gi * PP;
    int ph = pp / PW, pw = pp - ph * PW;
    int gl = gi >> 5;
    float4 sc = *(const float4*)&bnp[gl * 128 + c4];
    float4 sh = *(const float4*)&bnp[gl * 128 + 64 + c4];
    const float* b = raw + (((size_t)gi * H + 2 * ph) * W + 2 * pw) * 64 + c4;
    float4 a00 = *(const float4*)b;
    float4 a01 = *(const float4*)(b + 64);
    float4 a10 = *(const float4*)(b + (size_t)W * 64);
    float4 a11 = *(const float4*)(b + (size_t)W * 64 + 64);
    float4 o;
    o.x = fmaxf(0.f, fmaxf(fmaxf(fmaf(sc.x, a00.x, sh.x), fmaf(sc.x, a01.x, sh.x)),
                           fmaxf(fmaf(sc.x, a10.x, sh.x), fmaf(sc.x, a11.x, sh.x))));
    o.y = fmaxf(0.f, fmaxf(fmaxf(fmaf(sc.y, a00.y, sh.y), fmaf(sc.y, a01.y, sh.y)),
                           fmaxf(fmaf(sc.y, a10.y, sh.y), fmaf(sc.y, a11.y, sh.y))));
    o.z = fmaxf(0.f, fmaxf(fmaxf(fmaf(sc.z, a00.z, sh.z), fmaf(sc.z, a01.z, sh.z)),
                           fmaxf(fmaf(sc.z, a10.z, sh.z), fmaf(sc.z, a11.z, sh.z))));
    o.w = fmaxf(0.f, fmaxf(fmaxf(fmaf(sc.w, a00.w, sh.w), fmaf(sc.w, a01.w, sh.w)),
                           fmaxf(fmaf(sc.w, a10.w, sh.w), fmaf(sc.w, a11.w, sh.w))));
    *(float4*)(outp + (size_t)pos * 64 + c4) = o;
}

// ---------------- LSTM + matching head (f32, proven) ------------------------
__global__ __launch_bounds__(128)
void xw_kernel(const float* __restrict__ emb, const float* __restrict__ fk,
               const float* __restrict__ bk, float* __restrict__ xwf,
               float* __restrict__ xwb) {
    int gi = blockIdx.x;
    int j = threadIdx.x;
    const float* e = emb + (size_t)gi * 1600;
    float a = 0.f, b = 0.f;
    for (int d = 0; d < 1600; ++d) {
        float ev = e[d];
        a = fmaf(ev, fk[(size_t)d * 128 + j], a);
        b = fmaf(ev, bk[(size_t)d * 128 + j], b);
    }
    xwf[(size_t)gi * 128 + j] = a;
    xwb[(size_t)gi * 128 + j] = b;
}

__global__ __launch_bounds__(64)
void lstm_kernel(const float* __restrict__ xwf, const float* __restrict__ xwb,
                 const float* __restrict__ fr, const float* __restrict__ fb,
                 const float* __restrict__ br, const float* __restrict__ bb,
                 float* __restrict__ Hs) {
    int g = blockIdx.x;
    int dir = blockIdx.y;
    int j = threadIdx.x;
    const float* xw = dir ? xwb : xwf;
    const float* Wr = dir ? br : fr;
    const float* bv = dir ? bb : fb;
    float frA[32], frB[32];
    #pragma unroll
    for (int k = 0; k < 32; ++k) {
        frA[k] = Wr[k * 128 + j];
        frB[k] = Wr[k * 128 + 64 + j];
    }
    float bA = bv[j], bB = bv[64 + j];
    float h = 0.f, c = 0.f;
    for (int st = 0; st < 32; ++st) {
        int t = dir ? (31 - st) : st;
        const float* xr = xw + ((size_t)g * NI + t) * 128;
        float accA = xr[j] + bA;
        float accB = xr[64 + j] + bB;
        #pragma unroll
        for (int k = 0; k < 32; ++k) {
            float hk = __shfl(h, k);
            accA = fmaf(hk, frA[k], accA);
            accB = fmaf(hk, frB[k], accB);
        }
        float ig = accA;
        float gg = accB;
        float fg = __shfl(accA, (j & 31) + 32);
        float og = __shfl(accB, (j & 31) + 32);
        float cn = sigm(fg) * c + sigm(ig) * tanhf(gg);
        float hn = sigm(og) * tanhf(cn);
        if (j < 32) {
            c = cn; h = hn;
            Hs[((size_t)g * NI + t) * 64 + dir * 32 + j] = hn;
        }
    }
}

__global__ __launch_bounds__(64)
void sim_kernel(const float* __restrict__ Hs, const int* __restrict__ ysup,
                const int* __restrict__ yq, float* __restrict__ ceb,
                float* __restrict__ eqb) {
    int q = blockIdx.x;
    int i = blockIdx.y;
    int lane = threadIdx.x;
    float qv = Hs[((size_t)(20 + q) * NI + i) * 64 + lane];
    float ls[20];
    for (int s = 0; s < 20; ++s) {
        float sv = Hs[((size_t)s * NI + i) * 64 + lane];
        float d = qv * sv;
        float m = sv * sv;
        #pragma unroll
        for (int o = 32; o > 0; o >>= 1) {
            d += __shfl_xor(d, o);
            m += __shfl_xor(m, o);
        }
        ls[s] = d * rsqrtf(fmaxf(m, 1e-10f));
    }
    if (lane == 0) {
        float mx = -1e30f;
        for (int s = 0; s < 20; ++s) mx = fmaxf(mx, ls[s]);
        float sum = 0.f, sim[20];
        for (int s = 0; s < 20; ++s) { sim[s] = expf(ls[s] - mx); sum += sim[s]; }
        float inv = 1.f / sum;
        float preds[20];
        for (int w = 0; w < 20; ++w) preds[w] = 0.f;
        for (int s = 0; s < 20; ++s) preds[ysup[i * 20 + s]] += sim[s] * inv;
        int y = yq[i * 5 + q];
        float pv = fminf(fmaxf(preds[y], 1e-7f), 1.f - 1e-7f);
        ceb[q * NI + i] = -logf(pv);
        int am = 0; float bm = preds[0];
        for (int w = 1; w < 20; ++w) if (preds[w] > bm) { bm = preds[w]; am = w; }
        eqb[q * NI + i] = (am == y) ? 1.f : 0.f;
    }
}

__global__ __launch_bounds__(64)
void final_kernel(const float* __restrict__ ceb, const float* __restrict__ eqb,
                  float* __restrict__ out) {
    int lane = threadIdx.x;
    float e = 0.f;
    if (lane < 32) {
        float ce = 0.f;
        for (int q = 0; q < 5; ++q) { ce += ceb[q * NI + lane]; e += eqb[q * NI + lane]; }
        out[lane] = ce * 0.2f;
    }
    #pragma unroll
    for (int o = 32; o > 0; o >>= 1) e += __shfl_xor(e, o);
    if (lane == 0) out[32] = e / 160.f;
}

__global__ void sentinel_kernel(float* out) {
    if (threadIdx.x < 33) out[threadIdx.x] = -777.25f;
}

extern "C" void kernel_launch(void* const* d_in, const int* in_sizes, int n_in,
                              void* d_out, int out_size, void* d_ws, size_t ws_size,
                              hipStream_t stream) {
    const float* xs   = (const float*)d_in[0];
    const int*   ysup = (const int*)  d_in[1];
    const float* xq   = (const float*)d_in[2];
    const int*   yq   = (const int*)  d_in[3];
    const float* k[4]  = { (const float*)d_in[4],  (const float*)d_in[8],
                           (const float*)d_in[12], (const float*)d_in[16] };
    const float* ga[4] = { (const float*)d_in[6],  (const float*)d_in[10],
                           (const float*)d_in[14], (const float*)d_in[18] };
    const float* be[4] = { (const float*)d_in[7],  (const float*)d_in[11],
                           (const float*)d_in[15], (const float*)d_in[19] };
    const float* fk = (const float*)d_in[20];
    const float* fr = (const float*)d_in[21];
    const float* fb = (const float*)d_in[22];
    const float* bk = (const float*)d_in[23];
    const float* br = (const float*)d_in[24];
    const float* bb = (const float*)d_in[25];
    float* out = (float*)d_out;

    // per-group float counts
    const size_t P1   = (size_t)NI * 42 * 42 * 64;
    const size_t P2   = (size_t)NI * 21 * 21 * 64;
    const size_t P3   = (size_t)NI * 10 * 10 * 64;
    const size_t R4   = (size_t)NI * 100 * 64;
    const size_t PERG = P1 + P2 + P3 + R4 + 21u * 32 * 128 + 128;
    const size_t FIXED = 1280000 + 2 * 102400 + 51200 + 320;

    const int cands[13] = {20, 18, 16, 14, 12, 10, 8, 6, 5, 4, 3, 2, 1};
    int C = 0;
    for (int t = 0; t < 13; ++t) {
        int c = cands[t];
        if (((size_t)c * PERG + FIXED) * sizeof(float) <= ws_size) { C = c; break; }
    }
    if (C == 0) {
        sentinel_kernel<<<1, 64, 0, stream>>>(out);
        return;
    }

    float* W = (float*)d_ws;
    size_t off = 0;
    float* pool1 = W + off; off += (size_t)C * P1;
    float* pool2 = W + off; off += (size_t)C * P2;
    float* pool3 = W + off; off += (size_t)C * P3;
    float* raw4  = W + off; off += (size_t)C * R4;
    float* emb   = W + off; off += 1280000;
    float* part  = W + off; off += 21u * (size_t)C * 32 * 128;
    float* bnp   = W + off; off += (size_t)C * 128;
    float* xwf   = W + off; off += 102400;
    float* xwb   = W + off; off += 102400;
    float* Hs    = W + off; off += 51200;
    float* ceb   = W + off; off += 160;
    float* eqb   = W + off; off += 160;

    for (int g0 = 0; g0 < NG; g0 += C) {
        int ngc = (NG - g0 < C) ? (NG - g0) : C;
        int gx = ngc * 32;

        // L1: conv3 + stats + pool -> pool1 (pre-BN)
        conv3pool_kernel<<<dim3(gx, 21), 256, 0, stream>>>(xs, xq, k[0], pool1, part, g0);
        bn_finalize_kernel<<<ngc, 256, 0, stream>>>(part, ga[0], be[0], bnp, 1.f / (32.f * 84 * 84), 21, gx);

        // L2: inline-BN(pool1) -> conv + stats + pool -> pool2 (pre-BN)
        conv64p_kernel<42, 8, 16><<<dim3(gx, 18), 256, 0, stream>>>(pool1, k[1], bnp, pool2, part);
        bn_finalize_kernel<<<ngc, 256, 0, stream>>>(part, ga[1], be[1], bnp, 1.f / (32.f * 42 * 42), 18, gx);

        // L3: inline-BN(pool2) -> conv + stats + pool -> pool3 (pre-BN)
        conv64p_kernel<21, 8, 8><<<dim3(gx, 9), 256, 0, stream>>>(pool2, k[2], bnp, pool3, part);
        bn_finalize_kernel<<<ngc, 256, 0, stream>>>(part, ga[2], be[2], bnp, 1.f / (32.f * 21 * 21), 9, gx);

        // L4: inline-BN(pool3) -> conv -> raw4; BN4+pool -> emb slice
        conv64_kernel<<<dim3(gx, 2), 256, 0, stream>>>(pool3, k[3], bnp, raw4, part, 10, 10);
        bn_finalize_kernel<<<ngc, 256, 0, stream>>>(part, ga[3], be[3], bnp, 1.f / (32.f * 100), 2, gx);
        bnpool_kernel<<<(gx * 25 * 16 + 255) / 256, 256, 0, stream>>>(raw4, bnp, emb + (size_t)g0 * 32 * 1600, 10, 10, 5, 5, gx * 25 * 16);
    }

    xw_kernel<<<800, 128, 0, stream>>>(emb, fk, bk, xwf, xwb);
    lstm_kernel<<<dim3(NG, 2), 64, 0, stream>>>(xwf, xwb, fr, fb, br, bb, Hs);
    sim_kernel<<<dim3(5, 32), 64, 0, stream>>>(Hs, ysup, yq, ceb, eqb);
    final_kernel<<<1, 64, 0, stream>>>(ceb, eqb, out);
}